// Round 3
// baseline (260.587 us; speedup 1.0000x reference)
//
#include <hip/hip_runtime.h>
#include <math.h>

#define TPB 256
#define KTOP 10

__device__ __forceinline__ bool read_maskgt(const void* p, int i) {
    const unsigned char* b = (const unsigned char*)p;
    // counts >= 8 so mask_gt[0][1] is always true: byte[1]!=0 <=> bool-byte layout.
    if (b[1] != 0) return b[i] != 0;
    // int32 (value 0/1) or float32 (bits of 0.0/1.0) both: nonzero word == true
    return ((const int*)p)[i] != 0;
}

// ---------------- K0: zero outputs + num_pts accumulators ----------------
__global__ void k0_init(float* out, int* numpts, int bs) {
    int t = threadIdx.x;
    if (t < 3) out[t] = 0.0f;
    if (t < bs) numpts[t] = 0;
}

// ---------------- K1: per-(b,a) class sums S, Se ----------------
__global__ void k1_scores(const float* __restrict__ ps, float* __restrict__ S,
                          float* __restrict__ Se, int rows, int NC) {
    int r = blockIdx.x * 4 + (threadIdx.x >> 6);
    int lane = threadIdx.x & 63;
    if (r >= rows) return;
    const float* row = ps + (long)r * NC;
    float s = 0.f, se = 0.f;
    for (int c = lane; c < NC; c += 64) {
        float p = row[c];
        s  += -fmaxf(logf(1.0f - p), -100.0f);
        se += -logf(1.0f - p + 1e-7f);
    }
    for (int off = 32; off; off >>= 1) {
        s  += __shfl_down(s, off);
        se += __shfl_down(se, off);
    }
    if (lane == 0) { S[r] = s; Se[r] = se; }
}

// ---------------- K2: cost matrix + top-k selection per (b,g) ----------------
__global__ void k2_cost(const float* __restrict__ pred_boxes,
                        const float* __restrict__ gt_boxes,
                        const void*  mask_gt,
                        const float* __restrict__ ps,
                        const int*   __restrict__ labels,
                        const float* __restrict__ anchors,
                        const float* __restrict__ strides,
                        const float* __restrict__ S,
                        float* __restrict__ cost,
                        unsigned char* __restrict__ mask,
                        int G, int HW, int NC) {
    __shared__ float ls_cv[TPB * KTOP];
    __shared__ int   ls_ci[TPB * KTOP];
    __shared__ float ls_iv[TPB * KTOP];
    __shared__ float red_v[4];
    __shared__ int   red_a[4];
    __shared__ int   red_p[4];
    __shared__ int   sh_wp;
    __shared__ int   sel[KTOP];
    __shared__ int   sh_ptn;

    int tid = threadIdx.x;
    int pair = blockIdx.x;
    int b = pair / G;
    float* crow = cost + (long)pair * HW;
    unsigned char* mrow = mask + (long)pair * HW;

    bool valid = read_maskgt(mask_gt, pair);
    if (!valid) {
        for (int a = tid; a < HW; a += TPB) { crow[a] = 1e6f; mrow[a] = 0; }
        return;
    }

    int lab = labels[pair];
    const float4 gb = ((const float4*)gt_boxes)[pair];
    const float gx1 = gb.x, gy1 = gb.y, gx2 = gb.z, gy2 = gb.w;
    const float ctrx = (gx1 + gx2) * 0.5f, ctry = (gy1 + gy2) * 0.5f;
    const float w2 = gx2 - gx1, h2 = gy2 - gy1 + 1e-9f;

    float cv[KTOP]; int ci[KTOP]; float iv[KTOP];
#pragma unroll
    for (int j = 0; j < KTOP; ++j) { cv[j] = 3e38f; ci[j] = 0x7fffffff; iv[j] = -3e38f; }

    const float* pbb  = pred_boxes + (long)b * HW * 4;
    const float* Srow = S + (long)b * HW;
    const float* psb  = ps + (long)b * HW * NC;

    for (int a = tid; a < HW; a += TPB) {
        float4 pb = ((const float4*)pbb)[a];
        float ax = anchors[2 * a], ay = anchors[2 * a + 1];
        float st = strides[a];
        float apx = (ax + 0.5f) * st, apy = (ay + 0.5f) * st;
        bool in_boxes = (apx - gx1 > 0.f) & (apy - gy1 > 0.f) &
                        (gx2 - apx > 0.f) & (gy2 - apy > 0.f);
        float dis = 2.5f * st;
        bool in_centers = (apx - (ctrx - dis) > 0.f) & (apy - (ctry - dis) > 0.f) &
                          ((ctrx + dis) - apx > 0.f) & ((ctry + dis) - apy > 0.f);
        bool fg = in_boxes | in_centers;
        bool in_both = in_boxes & in_centers;

        float w1 = pb.z - pb.x, h1 = pb.w - pb.y + 1e-9f;
        float iw = fminf(pb.z, gx2) - fmaxf(pb.x, gx1);
        float ih = fminf(pb.w, gy2) - fmaxf(pb.y, gy1);
        float inter = fmaxf(iw, 0.f) * fmaxf(ih, 0.f);
        float uni = w1 * h1 + w2 * h2 - inter + 1e-9f;
        float iou = inter / uni;
        float iou_cost = -logf(iou + 1e-7f);

        float pl = psb[(long)a * NC + lab];
        float nll0 = -fmaxf(logf(pl), -100.f);
        float nll1 = -fmaxf(logf(1.f - pl), -100.f);
        float cls = Srow[a] + (fg ? (nll0 - nll1) : 0.f);
        float c = cls + 3.f * iou_cost + (in_both ? 0.f : 100000.f);
        crow[a] = c;
        mrow[a] = 0;

        // top-10 smallest cost (stable tie-break by index, matching stable argsort)
        if (c < cv[KTOP - 1] || (c == cv[KTOP - 1] && a < ci[KTOP - 1])) {
            cv[KTOP - 1] = c; ci[KTOP - 1] = a;
#pragma unroll
            for (int j = KTOP - 1; j >= 1; --j) {
                bool sw = (cv[j] < cv[j - 1]) || (cv[j] == cv[j - 1] && ci[j] < ci[j - 1]);
                if (sw) {
                    float tv = cv[j]; cv[j] = cv[j - 1]; cv[j - 1] = tv;
                    int ti = ci[j]; ci[j] = ci[j - 1]; ci[j - 1] = ti;
                }
            }
        }
        // top-10 largest fg-masked iou
        float ivl = fg ? iou : -3e38f;
        if (ivl > iv[KTOP - 1]) {
            iv[KTOP - 1] = ivl;
#pragma unroll
            for (int j = KTOP - 1; j >= 1; --j) {
                if (iv[j] > iv[j - 1]) { float tv = iv[j]; iv[j] = iv[j - 1]; iv[j - 1] = tv; }
            }
        }
    }

#pragma unroll
    for (int j = 0; j < KTOP; ++j) {
        ls_cv[tid * KTOP + j] = cv[j];
        ls_ci[tid * KTOP + j] = ci[j];
        ls_iv[tid * KTOP + j] = iv[j];
    }
    __syncthreads();

    // ---- 10 rounds: global argmax of iou; thread0 accumulates the sum ----
    float ptsum = 0.f;
    for (int r = 0; r < KTOP; ++r) {
        float bv = -3e38f; int bp = -1;
#pragma unroll
        for (int j = 0; j < KTOP; ++j) {
            float v = ls_iv[tid * KTOP + j];
            if (v > bv) { bv = v; bp = tid * KTOP + j; }
        }
        for (int off = 32; off; off >>= 1) {
            float ov = __shfl_down(bv, off); int op = __shfl_down(bp, off);
            if (ov > bv) { bv = ov; bp = op; }
        }
        if ((tid & 63) == 0) { red_v[tid >> 6] = bv; red_p[tid >> 6] = bp; }
        __syncthreads();
        if (tid == 0) {
            float gv = red_v[0]; int gp = red_p[0];
#pragma unroll
            for (int w = 1; w < 4; ++w)
                if (red_v[w] > gv) { gv = red_v[w]; gp = red_p[w]; }
            ptsum += fmaxf(gv, 0.f);   // -inf sentinel -> 0 (isfinite semantics)
            sh_wp = gp;
        }
        __syncthreads();
        if (sh_wp >= tid * KTOP && sh_wp < (tid + 1) * KTOP) ls_iv[sh_wp] = -3e38f;
        __syncthreads();
    }
    if (tid == 0) sh_ptn = (int)fmaxf(ptsum, 1.0f);   // trunc toward zero, in [1,10]

    // ---- 10 rounds: global argmin of (cost, idx) ----
    for (int r = 0; r < KTOP; ++r) {
        float bv = 3e38f; int ba = 0x7fffffff; int bp = -1;
#pragma unroll
        for (int j = 0; j < KTOP; ++j) {
            float v = ls_cv[tid * KTOP + j]; int ai = ls_ci[tid * KTOP + j];
            if (v < bv || (v == bv && ai < ba)) { bv = v; ba = ai; bp = tid * KTOP + j; }
        }
        for (int off = 32; off; off >>= 1) {
            float ov = __shfl_down(bv, off);
            int oa = __shfl_down(ba, off);
            int op = __shfl_down(bp, off);
            if (ov < bv || (ov == bv && oa < ba)) { bv = ov; ba = oa; bp = op; }
        }
        if ((tid & 63) == 0) { red_v[tid >> 6] = bv; red_a[tid >> 6] = ba; red_p[tid >> 6] = bp; }
        __syncthreads();
        if (tid == 0) {
            float gv = red_v[0]; int ga = red_a[0]; int gp = red_p[0];
#pragma unroll
            for (int w = 1; w < 4; ++w)
                if (red_v[w] < gv || (red_v[w] == gv && red_a[w] < ga)) {
                    gv = red_v[w]; ga = red_a[w]; gp = red_p[w];
                }
            sel[r] = ga; sh_wp = gp;
        }
        __syncthreads();
        if (sh_wp >= tid * KTOP && sh_wp < (tid + 1) * KTOP) {
            ls_cv[sh_wp] = 3e38f; ls_ci[sh_wp] = 0x7fffffff;
        }
        __syncthreads();
    }
    if (tid < sh_ptn) mrow[sel[tid]] = 1;
}

// ---------------- K3: per-anchor reassignment + num_pts ----------------
__global__ void k3_assign(const float* __restrict__ cost,
                          unsigned char* __restrict__ mask,
                          unsigned char* __restrict__ gtconf,
                          int* __restrict__ numpts,
                          int G, int HW) {
    __shared__ int red[TPB];
    int b = blockIdx.y;
    int a = blockIdx.x * TPB + threadIdx.x;
    int cntf = 0;
    if (a < HW) {
        float bestc = 3.4e38f; int best = 0; int cnt = 0; unsigned int bits = 0;
        for (int g = 0; g < G; ++g) {
            long idx = ((long)(b * G + g)) * HW + a;
            float c = cost[idx];
            if (c < bestc) { bestc = c; best = g; }   // first occurrence wins (argmin)
            unsigned char mm = mask[idx];
            cnt += mm;
            bits |= ((unsigned int)(mm != 0)) << g;
        }
        if (cnt > 1) bits = 1u << best;
        for (int g = 0; g < G; ++g)
            mask[((long)(b * G + g)) * HW + a] = (unsigned char)((bits >> g) & 1u);
        cntf = (cnt > 1) ? 1 : cnt;
        gtconf[(long)b * HW + a] = (unsigned char)(cntf > 0 ? 1 : 0);
    }
    red[threadIdx.x] = cntf;
    __syncthreads();
    for (int s = TPB / 2; s; s >>= 1) {
        if (threadIdx.x < s) red[threadIdx.x] += red[threadIdx.x + s];
        __syncthreads();
    }
    if (threadIdx.x == 0 && red[0] > 0) atomicAdd(&numpts[b], red[0]);
}

// ---------------- K4a: l0 (CIoU) + l1 (cls BCE) over masked pairs ----------------
__global__ void k4_pair(const float* __restrict__ pred_boxes,
                        const float* __restrict__ gt_boxes,
                        const float* __restrict__ ps,
                        const int*   __restrict__ labels,
                        const float* __restrict__ Se,
                        const unsigned char* __restrict__ mask,
                        const int* __restrict__ numpts,
                        float* __restrict__ out,
                        int G, int HW, int NC) {
    __shared__ float r0[TPB];
    __shared__ float r1[TPB];
    int tid = threadIdx.x;
    int pair = blockIdx.x;
    int b = pair / G;
    const unsigned char* mrow = mask + (long)pair * HW;
    const float4 gb = ((const float4*)gt_boxes)[pair];
    float gx1 = gb.x, gy1 = gb.y, gx2 = gb.z, gy2 = gb.w;
    float w2 = gx2 - gx1, h2 = gy2 - gy1 + 1e-9f;
    int lab = labels[pair];
    const float* pbb   = pred_boxes + (long)b * HW * 4;
    const float* psb   = ps + (long)b * HW * NC;
    const float* Serow = Se + (long)b * HW;
    float at2 = atanf(w2 / h2);
    float s0 = 0.f, s1 = 0.f;
    for (int a = tid; a < HW; a += TPB) {
        if (!mrow[a]) continue;
        float4 pb = ((const float4*)pbb)[a];
        float w1 = pb.z - pb.x, h1 = pb.w - pb.y + 1e-9f;
        float iw = fminf(pb.z, gx2) - fmaxf(pb.x, gx1);
        float ih = fminf(pb.w, gy2) - fmaxf(pb.y, gy1);
        float inter = fmaxf(iw, 0.f) * fmaxf(ih, 0.f);
        float uni = w1 * h1 + w2 * h2 - inter + 1e-9f;
        float iou = inter / uni;
        float cw = fmaxf(pb.z, gx2) - fminf(pb.x, gx1);
        float ch = fmaxf(pb.w, gy2) - fminf(pb.y, gy1);
        float c2 = cw * cw + ch * ch + 1e-9f;
        float dx = gx1 + gx2 - pb.x - pb.z;
        float dy = gy1 + gy2 - pb.y - pb.w;
        float d2 = (dx * dx + dy * dy) * 0.25f;
        float dat = at2 - atanf(w1 / h1);
        float v = 0.4052847345693511f * dat * dat;   // 4/pi^2
        float alpha = v / (v - iou + 1.0f);          // (1.0+1e-9) rounds to 1.0f
        float ciou = iou - (d2 / c2 + v * alpha);
        s0 += 1.0f - ciou;
        float pl = psb[(long)a * NC + lab];
        s1 += Serow[a] - logf(pl + 1e-7f) + logf(1.f - pl + 1e-7f);
    }
    r0[tid] = s0; r1[tid] = s1;
    __syncthreads();
    for (int s = TPB / 2; s; s >>= 1) {
        if (tid < s) { r0[tid] += r0[tid + s]; r1[tid] += r1[tid + s]; }
        __syncthreads();
    }
    if (tid == 0 && (r0[0] != 0.f || r1[0] != 0.f)) {
        float np = (float)numpts[b];
        atomicAdd(out + 0, r0[0] / np);
        atomicAdd(out + 1, r1[0] / np);
    }
}

// ---------------- K4b: l2 (objectness BCE) ----------------
__global__ void k4_conf(const float* __restrict__ pred_conf,
                        const unsigned char* __restrict__ gtconf,
                        const int* __restrict__ numpts,
                        float* __restrict__ out, int HW) {
    __shared__ float red[TPB];
    int b = blockIdx.y;
    int a = blockIdx.x * TPB + threadIdx.x;
    float v = 0.f;
    if (a < HW) {
        float pc = pred_conf[(long)b * HW + a];
        v = gtconf[(long)b * HW + a] ? -logf(pc + 1e-7f) : -logf(1.f - pc + 1e-7f);
    }
    red[threadIdx.x] = v;
    __syncthreads();
    for (int s = TPB / 2; s; s >>= 1) {
        if (threadIdx.x < s) red[threadIdx.x] += red[threadIdx.x + s];
        __syncthreads();
    }
    if (threadIdx.x == 0) atomicAdd(out + 2, red[0] / (float)numpts[b]);
}

extern "C" void kernel_launch(void* const* d_in, const int* in_sizes, int n_in,
                              void* d_out, int out_size, void* d_ws, size_t ws_size,
                              hipStream_t stream) {
    const float* pred_boxes = (const float*)d_in[0];
    const float* gt_boxes   = (const float*)d_in[1];
    const void*  mask_gt    = d_in[2];
    const float* ps         = (const float*)d_in[3];
    const float* pred_conf  = (const float*)d_in[4];
    const int*   gt_labels  = (const int*)d_in[5];
    const float* anchors    = (const float*)d_in[6];
    const float* strides    = (const float*)d_in[7];
    float* out = (float*)d_out;

    const int HW = in_sizes[7];               // stride_tensor: hw
    const int BS = in_sizes[4] / HW;          // pred_conf: bs*hw
    const int G  = in_sizes[5] / BS;          // gt_labels: bs*G
    const int NC = in_sizes[3] / (BS * HW);   // pred_scores: bs*hw*nc

    char* w = (char*)d_ws;
    float* S  = (float*)w;                    w += (size_t)BS * HW * 4;
    float* Se = (float*)w;                    w += (size_t)BS * HW * 4;
    float* cost = (float*)w;                  w += (size_t)BS * G * HW * 4;
    int* numpts = (int*)w;                    w += 256;
    unsigned char* mask   = (unsigned char*)w; w += (size_t)BS * G * HW;
    unsigned char* gtconf = (unsigned char*)w;

    k0_init<<<1, 64, 0, stream>>>(out, numpts, BS);

    int rows = BS * HW;
    k1_scores<<<(rows + 3) / 4, TPB, 0, stream>>>(ps, S, Se, rows, NC);

    k2_cost<<<BS * G, TPB, 0, stream>>>(pred_boxes, gt_boxes, mask_gt, ps, gt_labels,
                                        anchors, strides, S, cost, mask, G, HW, NC);

    dim3 g3((HW + TPB - 1) / TPB, BS);
    k3_assign<<<g3, TPB, 0, stream>>>(cost, mask, gtconf, numpts, G, HW);

    k4_pair<<<BS * G, TPB, 0, stream>>>(pred_boxes, gt_boxes, ps, gt_labels, Se,
                                        mask, numpts, out, G, HW, NC);

    k4_conf<<<g3, TPB, 0, stream>>>(pred_conf, gtconf, numpts, out, HW);
}

// Round 5
// 251.777 us; speedup vs baseline: 1.0350x; 1.0350x over previous
//
#include <hip/hip_runtime.h>
#include <math.h>

#define TPB 256
#define KTOP 10
#define GMAX 32

__device__ __forceinline__ bool read_maskgt(const void* p, int i) {
    const unsigned char* b = (const unsigned char*)p;
    // counts >= 8 so mask_gt[0][1] is always true: byte[1]!=0 <=> bool-byte layout.
    if (b[1] != 0) return b[i] != 0;
    // int32 (value 0/1) or float32 (bits of 0.0/1.0) both: nonzero word == true
    return ((const int*)p)[i] != 0;
}

// ---------------- K0: zero outputs + num_pts accumulators ----------------
__global__ void k0_init(float* out, int* numpts, int bs) {
    int t = threadIdx.x;
    if (t < 3) out[t] = 0.0f;
    if (t < bs) numpts[t] = 0;
}

// ---------------- K1: per-(b,a) class sums S, Se ----------------
__global__ void k1_scores(const float* __restrict__ ps, float* __restrict__ S,
                          float* __restrict__ Se, int rows, int NC) {
    int r = blockIdx.x * 4 + (threadIdx.x >> 6);
    int lane = threadIdx.x & 63;
    if (r >= rows) return;
    const float* row = ps + (long)r * NC;
    float s = 0.f, se = 0.f;
    for (int c = lane; c < NC; c += 64) {
        float p = row[c];
        s  += -fmaxf(logf(1.0f - p), -100.0f);
        se += -logf(1.0f - p + 1e-7f);
    }
    for (int off = 32; off; off >>= 1) {
        s  += __shfl_down(s, off);
        se += __shfl_down(se, off);
    }
    if (lane == 0) { S[r] = s; Se[r] = se; }
}

// ---------------- K2a: fused cost over all g per anchor (row-local gather) ----
// grid = (ceil(HW/TPB), BS). Thread = one anchor. The 32 label values live in
// the thread's own 320B ps row -> ~5 cachelines, tight reuse, L1-friendly.
// Writes cost[b][g][a] (coalesced per g), mask=0, best[b][a]=argmin_g cost.
__global__ void k2a_cost(const float* __restrict__ pred_boxes,
                         const float* __restrict__ gt_boxes,
                         const void*  mask_gt,
                         const float* __restrict__ ps,
                         const int*   __restrict__ labels,
                         const float* __restrict__ anchors,
                         const float* __restrict__ strides,
                         const float* __restrict__ S,
                         float* __restrict__ cost,
                         unsigned char* __restrict__ mask,
                         unsigned char* __restrict__ best,
                         int G, int HW, int NC) {
    __shared__ float4 s_gb[GMAX];
    __shared__ float  s_ctrx[GMAX], s_ctry[GMAX];
    __shared__ int    s_lab[GMAX];
    __shared__ int    s_val[GMAX];

    int b = blockIdx.y;
    int tid = threadIdx.x;
    if (tid < G) {
        int pr = b * G + tid;
        float4 gb = ((const float4*)gt_boxes)[pr];
        s_gb[tid] = gb;
        s_ctrx[tid] = (gb.x + gb.z) * 0.5f;
        s_ctry[tid] = (gb.y + gb.w) * 0.5f;
        s_lab[tid] = labels[pr];
        s_val[tid] = read_maskgt(mask_gt, pr) ? 1 : 0;
    }
    __syncthreads();

    int a = blockIdx.x * TPB + tid;
    if (a >= HW) return;

    const float4 pb = ((const float4*)(pred_boxes + (long)b * HW * 4))[a];
    float ax = anchors[2 * a], ay = anchors[2 * a + 1];
    float st = strides[a];
    float apx = (ax + 0.5f) * st, apy = (ay + 0.5f) * st;
    float dis = 2.5f * st;
    float Sa = S[(long)b * HW + a];
    float w1 = pb.z - pb.x, h1 = pb.w - pb.y + 1e-9f;
    float w1h1 = w1 * h1;
    const float* __restrict__ row = ps + ((long)b * HW + a) * NC;

    float bestc = 3.4e38f;
    int bestg = 0;

#pragma unroll
    for (int g = 0; g < GMAX; ++g) {
        if (g >= G) break;
        long oidx = ((long)(b * G + g)) * HW + a;
        float c;
        if (!s_val[g]) {
            c = 1e6f;
        } else {
            float pl = row[s_lab[g]];
            float4 gb = s_gb[g];
            float gx1 = gb.x, gy1 = gb.y, gx2 = gb.z, gy2 = gb.w;
            bool in_boxes = (apx - gx1 > 0.f) & (apy - gy1 > 0.f) &
                            (gx2 - apx > 0.f) & (gy2 - apy > 0.f);
            float ctrx = s_ctrx[g], ctry = s_ctry[g];
            bool in_centers = (apx - (ctrx - dis) > 0.f) & (apy - (ctry - dis) > 0.f) &
                              ((ctrx + dis) - apx > 0.f) & ((ctry + dis) - apy > 0.f);
            bool fg = in_boxes | in_centers;
            bool in_both = in_boxes & in_centers;

            float w2 = gx2 - gx1, h2 = gy2 - gy1 + 1e-9f;
            float iw = fminf(pb.z, gx2) - fmaxf(pb.x, gx1);
            float ih = fminf(pb.w, gy2) - fmaxf(pb.y, gy1);
            float inter = fmaxf(iw, 0.f) * fmaxf(ih, 0.f);
            float uni = w1h1 + w2 * h2 - inter + 1e-9f;
            float iou = inter / uni;
            float iou_cost = -logf(iou + 1e-7f);

            float nll0 = -fmaxf(logf(pl), -100.f);
            float nll1 = -fmaxf(logf(1.f - pl), -100.f);
            float cls = Sa + (fg ? (nll0 - nll1) : 0.f);
            c = cls + 3.f * iou_cost + (in_both ? 0.f : 100000.f);
        }
        cost[oidx] = c;
        mask[oidx] = 0;
        if (c < bestc) { bestc = c; bestg = g; }   // first occurrence wins
    }
    best[(long)b * HW + a] = (unsigned char)bestg;
}

// ---------------- K2b: top-k selection per (b,g) (reads cost, no gather) ----
__global__ void k2b_select(const float* __restrict__ pred_boxes,
                           const float* __restrict__ gt_boxes,
                           const void*  mask_gt,
                           const float* __restrict__ anchors,
                           const float* __restrict__ strides,
                           const float* __restrict__ cost,
                           unsigned char* __restrict__ mask,
                           int G, int HW) {
    __shared__ float ls_cv[TPB * KTOP];
    __shared__ int   ls_ci[TPB * KTOP];
    __shared__ float ls_iv[TPB * KTOP];
    __shared__ float red_v[4];
    __shared__ int   red_a[4];
    __shared__ int   red_p[4];
    __shared__ int   sh_wp;
    __shared__ int   sel[KTOP];
    __shared__ int   sh_ptn;

    int tid = threadIdx.x;
    int pair = blockIdx.x;
    int b = pair / G;

    if (!read_maskgt(mask_gt, pair)) return;   // cost/mask already written by k2a

    const float* crow = cost + (long)pair * HW;
    unsigned char* mrow = mask + (long)pair * HW;

    const float4 gb = ((const float4*)gt_boxes)[pair];
    const float gx1 = gb.x, gy1 = gb.y, gx2 = gb.z, gy2 = gb.w;
    const float ctrx = (gx1 + gx2) * 0.5f, ctry = (gy1 + gy2) * 0.5f;
    const float w2 = gx2 - gx1, h2 = gy2 - gy1 + 1e-9f;

    float cv[KTOP]; int ci[KTOP]; float iv[KTOP];
#pragma unroll
    for (int j = 0; j < KTOP; ++j) { cv[j] = 3e38f; ci[j] = 0x7fffffff; iv[j] = -3e38f; }

    const float* pbb = pred_boxes + (long)b * HW * 4;

    for (int a = tid; a < HW; a += TPB) {
        float4 pb = ((const float4*)pbb)[a];
        float ax = anchors[2 * a], ay = anchors[2 * a + 1];
        float st = strides[a];
        float apx = (ax + 0.5f) * st, apy = (ay + 0.5f) * st;
        bool in_boxes = (apx - gx1 > 0.f) & (apy - gy1 > 0.f) &
                        (gx2 - apx > 0.f) & (gy2 - apy > 0.f);
        float dis = 2.5f * st;
        bool in_centers = (apx - (ctrx - dis) > 0.f) & (apy - (ctry - dis) > 0.f) &
                          ((ctrx + dis) - apx > 0.f) & ((ctry + dis) - apy > 0.f);
        bool fg = in_boxes | in_centers;

        float w1 = pb.z - pb.x, h1 = pb.w - pb.y + 1e-9f;
        float iw = fminf(pb.z, gx2) - fmaxf(pb.x, gx1);
        float ih = fminf(pb.w, gy2) - fmaxf(pb.y, gy1);
        float inter = fmaxf(iw, 0.f) * fmaxf(ih, 0.f);
        float uni = w1 * h1 + w2 * h2 - inter + 1e-9f;
        float iou = inter / uni;

        float c = crow[a];

        // top-10 smallest cost (stable tie-break by index, matching stable argsort)
        if (c < cv[KTOP - 1] || (c == cv[KTOP - 1] && a < ci[KTOP - 1])) {
            cv[KTOP - 1] = c; ci[KTOP - 1] = a;
#pragma unroll
            for (int j = KTOP - 1; j >= 1; --j) {
                bool sw = (cv[j] < cv[j - 1]) || (cv[j] == cv[j - 1] && ci[j] < ci[j - 1]);
                if (sw) {
                    float tv = cv[j]; cv[j] = cv[j - 1]; cv[j - 1] = tv;
                    int ti = ci[j]; ci[j] = ci[j - 1]; ci[j - 1] = ti;
                }
            }
        }
        // top-10 largest fg-masked iou
        float ivl = fg ? iou : -3e38f;
        if (ivl > iv[KTOP - 1]) {
            iv[KTOP - 1] = ivl;
#pragma unroll
            for (int j = KTOP - 1; j >= 1; --j) {
                if (iv[j] > iv[j - 1]) { float tv = iv[j]; iv[j] = iv[j - 1]; iv[j - 1] = tv; }
            }
        }
    }

#pragma unroll
    for (int j = 0; j < KTOP; ++j) {
        ls_cv[tid * KTOP + j] = cv[j];
        ls_ci[tid * KTOP + j] = ci[j];
        ls_iv[tid * KTOP + j] = iv[j];
    }
    __syncthreads();

    // ---- 10 rounds: global argmax of iou; thread0 accumulates the sum ----
    float ptsum = 0.f;
    for (int r = 0; r < KTOP; ++r) {
        float bv = -3e38f; int bp = -1;
#pragma unroll
        for (int j = 0; j < KTOP; ++j) {
            float v = ls_iv[tid * KTOP + j];
            if (v > bv) { bv = v; bp = tid * KTOP + j; }
        }
        for (int off = 32; off; off >>= 1) {
            float ov = __shfl_down(bv, off); int op = __shfl_down(bp, off);
            if (ov > bv) { bv = ov; bp = op; }
        }
        if ((tid & 63) == 0) { red_v[tid >> 6] = bv; red_p[tid >> 6] = bp; }
        __syncthreads();
        if (tid == 0) {
            float gv = red_v[0]; int gp = red_p[0];
#pragma unroll
            for (int w = 1; w < 4; ++w)
                if (red_v[w] > gv) { gv = red_v[w]; gp = red_p[w]; }
            ptsum += fmaxf(gv, 0.f);   // -inf sentinel -> 0 (isfinite semantics)
            sh_wp = gp;
        }
        __syncthreads();
        if (sh_wp >= tid * KTOP && sh_wp < (tid + 1) * KTOP) ls_iv[sh_wp] = -3e38f;
        __syncthreads();
    }
    if (tid == 0) sh_ptn = (int)fmaxf(ptsum, 1.0f);   // trunc toward zero, in [1,10]

    // ---- 10 rounds: global argmin of (cost, idx) ----
    for (int r = 0; r < KTOP; ++r) {
        float bv = 3e38f; int ba = 0x7fffffff; int bp = -1;
#pragma unroll
        for (int j = 0; j < KTOP; ++j) {
            float v = ls_cv[tid * KTOP + j]; int ai = ls_ci[tid * KTOP + j];
            if (v < bv || (v == bv && ai < ba)) { bv = v; ba = ai; bp = tid * KTOP + j; }
        }
        for (int off = 32; off; off >>= 1) {
            float ov = __shfl_down(bv, off);
            int oa = __shfl_down(ba, off);
            int op = __shfl_down(bp, off);
            if (ov < bv || (ov == bv && oa < ba)) { bv = ov; ba = oa; bp = op; }
        }
        if ((tid & 63) == 0) { red_v[tid >> 6] = bv; red_a[tid >> 6] = ba; red_p[tid >> 6] = bp; }
        __syncthreads();
        if (tid == 0) {
            float gv = red_v[0]; int ga = red_a[0]; int gp = red_p[0];
#pragma unroll
            for (int w = 1; w < 4; ++w)
                if (red_v[w] < gv || (red_v[w] == gv && red_a[w] < ga)) {
                    gv = red_v[w]; ga = red_a[w]; gp = red_p[w];
                }
            sel[r] = ga; sh_wp = gp;
        }
        __syncthreads();
        if (sh_wp >= tid * KTOP && sh_wp < (tid + 1) * KTOP) {
            ls_cv[sh_wp] = 3e38f; ls_ci[sh_wp] = 0x7fffffff;
        }
        __syncthreads();
    }
    if (tid < sh_ptn) mrow[sel[tid]] = 1;
}

// ---------------- K3: per-anchor reassignment + num_pts ----------------
__global__ void k3_assign(const unsigned char* __restrict__ best,
                          unsigned char* __restrict__ mask,
                          unsigned char* __restrict__ gtconf,
                          int* __restrict__ numpts,
                          int G, int HW) {
    __shared__ int red[TPB];
    int b = blockIdx.y;
    int a = blockIdx.x * TPB + threadIdx.x;
    int cntf = 0;
    if (a < HW) {
        int cnt = 0;
        for (int g = 0; g < G; ++g)
            cnt += mask[((long)(b * G + g)) * HW + a];
        if (cnt > 1) {
            unsigned int bits = 1u << best[(long)b * HW + a];
            for (int g = 0; g < G; ++g)
                mask[((long)(b * G + g)) * HW + a] = (unsigned char)((bits >> g) & 1u);
        }
        cntf = (cnt > 1) ? 1 : cnt;
        gtconf[(long)b * HW + a] = (unsigned char)(cntf > 0 ? 1 : 0);
    }
    red[threadIdx.x] = cntf;
    __syncthreads();
    for (int s = TPB / 2; s; s >>= 1) {
        if (threadIdx.x < s) red[threadIdx.x] += red[threadIdx.x + s];
        __syncthreads();
    }
    if (threadIdx.x == 0 && red[0] > 0) atomicAdd(&numpts[b], red[0]);
}

// ---------------- K4a: l0 (CIoU) + l1 (cls BCE) over masked pairs ----------------
__global__ void k4_pair(const float* __restrict__ pred_boxes,
                        const float* __restrict__ gt_boxes,
                        const float* __restrict__ ps,
                        const int*   __restrict__ labels,
                        const float* __restrict__ Se,
                        const unsigned char* __restrict__ mask,
                        const int* __restrict__ numpts,
                        float* __restrict__ out,
                        int G, int HW, int NC) {
    __shared__ float r0[TPB];
    __shared__ float r1[TPB];
    int tid = threadIdx.x;
    int pair = blockIdx.x;
    int b = pair / G;
    const unsigned char* mrow = mask + (long)pair * HW;
    const float4 gb = ((const float4*)gt_boxes)[pair];
    float gx1 = gb.x, gy1 = gb.y, gx2 = gb.z, gy2 = gb.w;
    float w2 = gx2 - gx1, h2 = gy2 - gy1 + 1e-9f;
    int lab = labels[pair];
    const float* pbb   = pred_boxes + (long)b * HW * 4;
    const float* psb   = ps + (long)b * HW * NC;
    const float* Serow = Se + (long)b * HW;
    float at2 = atanf(w2 / h2);
    float s0 = 0.f, s1 = 0.f;
    for (int a = tid; a < HW; a += TPB) {
        if (!mrow[a]) continue;
        float4 pb = ((const float4*)pbb)[a];
        float w1 = pb.z - pb.x, h1 = pb.w - pb.y + 1e-9f;
        float iw = fminf(pb.z, gx2) - fmaxf(pb.x, gx1);
        float ih = fminf(pb.w, gy2) - fmaxf(pb.y, gy1);
        float inter = fmaxf(iw, 0.f) * fmaxf(ih, 0.f);
        float uni = w1 * h1 + w2 * h2 - inter + 1e-9f;
        float iou = inter / uni;
        float cw = fmaxf(pb.z, gx2) - fminf(pb.x, gx1);
        float ch = fmaxf(pb.w, gy2) - fminf(pb.y, gy1);
        float c2 = cw * cw + ch * ch + 1e-9f;
        float dx = gx1 + gx2 - pb.x - pb.z;
        float dy = gy1 + gy2 - pb.y - pb.w;
        float d2 = (dx * dx + dy * dy) * 0.25f;
        float dat = at2 - atanf(w1 / h1);
        float v = 0.4052847345693511f * dat * dat;   // 4/pi^2
        float alpha = v / (v - iou + 1.0f);          // (1.0+1e-9) rounds to 1.0f
        float ciou = iou - (d2 / c2 + v * alpha);
        s0 += 1.0f - ciou;
        float pl = psb[(long)a * NC + lab];
        s1 += Serow[a] - logf(pl + 1e-7f) + logf(1.f - pl + 1e-7f);
    }
    r0[tid] = s0; r1[tid] = s1;
    __syncthreads();
    for (int s = TPB / 2; s; s >>= 1) {
        if (tid < s) { r0[tid] += r0[tid + s]; r1[tid] += r1[tid + s]; }
        __syncthreads();
    }
    if (tid == 0 && (r0[0] != 0.f || r1[0] != 0.f)) {
        float np = (float)numpts[b];
        atomicAdd(out + 0, r0[0] / np);
        atomicAdd(out + 1, r1[0] / np);
    }
}

// ---------------- K4b: l2 (objectness BCE) ----------------
__global__ void k4_conf(const float* __restrict__ pred_conf,
                        const unsigned char* __restrict__ gtconf,
                        const int* __restrict__ numpts,
                        float* __restrict__ out, int HW) {
    __shared__ float red[TPB];
    int b = blockIdx.y;
    int a = blockIdx.x * TPB + threadIdx.x;
    float v = 0.f;
    if (a < HW) {
        float pc = pred_conf[(long)b * HW + a];
        v = gtconf[(long)b * HW + a] ? -logf(pc + 1e-7f) : -logf(1.f - pc + 1e-7f);
    }
    red[threadIdx.x] = v;
    __syncthreads();
    for (int s = TPB / 2; s; s >>= 1) {
        if (threadIdx.x < s) red[threadIdx.x] += red[threadIdx.x + s];
        __syncthreads();
    }
    if (threadIdx.x == 0) atomicAdd(out + 2, red[0] / (float)numpts[b]);
}

extern "C" void kernel_launch(void* const* d_in, const int* in_sizes, int n_in,
                              void* d_out, int out_size, void* d_ws, size_t ws_size,
                              hipStream_t stream) {
    const float* pred_boxes = (const float*)d_in[0];
    const float* gt_boxes   = (const float*)d_in[1];
    const void*  mask_gt    = d_in[2];
    const float* ps         = (const float*)d_in[3];
    const float* pred_conf  = (const float*)d_in[4];
    const int*   gt_labels  = (const int*)d_in[5];
    const float* anchors    = (const float*)d_in[6];
    const float* strides    = (const float*)d_in[7];
    float* out = (float*)d_out;

    const int HW = in_sizes[7];               // stride_tensor: hw
    const int BS = in_sizes[4] / HW;          // pred_conf: bs*hw
    const int G  = in_sizes[5] / BS;          // gt_labels: bs*G
    const int NC = in_sizes[3] / (BS * HW);   // pred_scores: bs*hw*nc

    char* w = (char*)d_ws;
    float* S  = (float*)w;                    w += (size_t)BS * HW * 4;
    float* Se = (float*)w;                    w += (size_t)BS * HW * 4;
    float* cost = (float*)w;                  w += (size_t)BS * G * HW * 4;
    int* numpts = (int*)w;                    w += 256;
    unsigned char* mask   = (unsigned char*)w; w += (size_t)BS * G * HW;
    unsigned char* gtconf = (unsigned char*)w; w += (size_t)BS * HW;
    unsigned char* best   = (unsigned char*)w;

    k0_init<<<1, 64, 0, stream>>>(out, numpts, BS);

    int rows = BS * HW;
    k1_scores<<<(rows + 3) / 4, TPB, 0, stream>>>(ps, S, Se, rows, NC);

    dim3 g2a((HW + TPB - 1) / TPB, BS);
    k2a_cost<<<g2a, TPB, 0, stream>>>(pred_boxes, gt_boxes, mask_gt, ps, gt_labels,
                                      anchors, strides, S, cost, mask, best, G, HW, NC);

    k2b_select<<<BS * G, TPB, 0, stream>>>(pred_boxes, gt_boxes, mask_gt, anchors,
                                           strides, cost, mask, G, HW);

    dim3 g3((HW + TPB - 1) / TPB, BS);
    k3_assign<<<g3, TPB, 0, stream>>>(best, mask, gtconf, numpts, G, HW);

    k4_pair<<<BS * G, TPB, 0, stream>>>(pred_boxes, gt_boxes, ps, gt_labels, Se,
                                        mask, numpts, out, G, HW, NC);

    k4_conf<<<g3, TPB, 0, stream>>>(pred_conf, gtconf, numpts, out, HW);
}